// Round 7
// baseline (37.796 us; speedup 1.0000x reference)
//
#include <hip/hip_runtime.h>
#include <math.h>

#define SEQ 4096
#define NBATCH 4
#define SGRP 16      // s-rows per attn block (one 16-row MFMA subtile)
#define TWAVES 8     // waves per attn block (t-split)
#define TCHUNK (SEQ / TWAVES)  // 512 t per wave
#define TT 16        // t-tile size

typedef _Float16 f16;
typedef __attribute__((ext_vector_type(4))) _Float16 f16x4;
typedef __attribute__((ext_vector_type(8))) _Float16 f16x8;
typedef __attribute__((ext_vector_type(4))) float f32x4;
typedef __attribute__((ext_vector_type(4))) short s16x4;

__device__ __forceinline__ float fexp2(float x) {
#if __has_builtin(__builtin_amdgcn_exp2f)
  return __builtin_amdgcn_exp2f(x);
#else
  return exp2f(x);
#endif
}

// float -> bf16 bits, RNE bit-twiddle. Verified numerics (R4/R5 passed).
// NOTE: R6's v_cvt_pk_bf16_f32 inline asm NaN'd — suspected dst-half-write
// semantics leaving stale garbage in high 16 bits. Do not reintroduce
// without an isolated probe.
__device__ __forceinline__ unsigned short f2bf(float f) {
  unsigned u = __builtin_bit_cast(unsigned, f);
  u += 0x7FFF + ((u >> 16) & 1);
  return (unsigned short)(u >> 16);
}

// Clifford Cl(3,0): sign of e_a * e_b (bitmask args).
__device__ __forceinline__ float cl_sign(int amask, int bmask) {
  int cnt = 0, aa = amask >> 1;
  while (aa) { cnt += __popc(aa & bmask); aa >>= 1; }
  return (cnt & 1) ? -1.f : 1.f;
}

// ---------------------------------------------------------------------------
// Kernel 1: fused {param-matrix build} + {Q/K/V projection & packing}.
//  Qp[row][16] f16 = [qhi(8) | qlo(8)]   (B-operand rows; hi/lo split)
//  Kp[row][8]  f16 = khi                  (A-operand; lanes re-read via hi&1)
//  Vt[b][c][t] bf16 bits, c=0..8: rows 0-7 = V blades, row 8 = ones (denom)
// ---------------------------------------------------------------------------
__global__ __launch_bounds__(128) void ck_qkv(const float* __restrict__ x,
                                              const float* __restrict__ wq,
                                              const float* __restrict__ bq,
                                              const float* __restrict__ wk,
                                              const float* __restrict__ bk,
                                              const float* __restrict__ wv,
                                              const float* __restrict__ bv,
                                              f16* __restrict__ Qp,
                                              f16* __restrict__ Kp,
                                              unsigned short* __restrict__ Vt) {
  __shared__ float Pl[288];
  const int blades[8] = {0, 1, 2, 4, 3, 5, 6, 7};
  int tid = threadIdx.x;

  if (tid < 64) {
    int j = tid >> 3, k = tid & 7;
    int bj = blades[j];
    float mq = 0.f, mk = 0.f, mv = 0.f;
    for (int i = 0; i < 8; ++i) {
      int ai = blades[i];
      if (blades[ai ^ bj] != k) continue;
      float sgn = cl_sign(ai, bj);
      mq += sgn * wq[i]; mk += sgn * wk[i]; mv += sgn * wv[i];
    }
    float c0 = cl_sign(blades[k], blades[k]);  // diagonal of scalar-part table
    const float F = 0.72134752044448170368f;   // 0.5 * log2(e)
    Pl[tid]       = mq * c0 * F;
    Pl[64 + tid]  = mk;
    Pl[128 + tid] = mv;
    if (j == 0) {
      Pl[256 + k] = bq[k] * c0 * F;
      Pl[264 + k] = bk[k];
      Pl[272 + k] = bv[k];
    }
  }
  __syncthreads();

  int row = blockIdx.x * 128 + tid;  // grid sized exactly to B*S
  int b = row >> 12;
  int s = row & (SEQ - 1);
  const float4* x4 = (const float4*)(x + (size_t)row * 8);
  float4 xa = x4[0], xb = x4[1];
  float xr[8] = {xa.x, xa.y, xa.z, xa.w, xb.x, xb.y, xb.z, xb.w};
  float q[8], k[8], v[8];
#pragma unroll
  for (int c = 0; c < 8; ++c) { q[c] = Pl[256 + c]; k[c] = Pl[264 + c]; v[c] = Pl[272 + c]; }
#pragma unroll
  for (int j = 0; j < 8; ++j) {
    float xj = xr[j];
#pragma unroll
    for (int c = 0; c < 8; ++c) {
      q[c] = fmaf(xj, Pl[j * 8 + c], q[c]);
      k[c] = fmaf(xj, Pl[64 + j * 8 + c], k[c]);
      v[c] = fmaf(xj, Pl[128 + j * 8 + c], v[c]);
    }
  }
  f16x8 qa, qb, ka;
#pragma unroll
  for (int c = 0; c < 8; ++c) {
    f16 h = (f16)q[c];
    qa[c] = h;
    qb[c] = (f16)(q[c] - (float)h);
    ka[c] = (f16)k[c];
  }
  f16x8* qrow = (f16x8*)(Qp + (size_t)row * 16);
  qrow[0] = qa; qrow[1] = qb;
  *(f16x8*)(Kp + (size_t)row * 8) = ka;
  unsigned short* vtb = Vt + (size_t)b * 9 * SEQ;
#pragma unroll
  for (int c = 0; c < 8; ++c) vtb[c * SEQ + s] = f2bf(v[c]);
  vtb[8 * SEQ + s] = 0x3F80;  // 1.0 bf16
}

// ---------------------------------------------------------------------------
// Kernel 2: MFMA flash attention, no-max softmax (bf16 P: no overflow).
// One block = 16 s-rows, 8 waves t-split (512 t each). 512-thr blocks give
// block-granular occupancy: 4 blocks/CU = 8 waves/SIMD at VGPR<=64.
// Per wave, per 16-t tile:
//   S^T = mfma_16x16x16f16(Kfrag, Qfrag, 0)
//     -> lane holds S[s=l&15][t0 + 4*(l>>4)+r], r=0..3
//   P = exp2(S) -> bf16 (B-frag of P^T for PV)
//   accT = mfma_16x16x16bf16_1k(VaugTfrag, Pfrag, accT)
//     -> lane holds O^T[c=4*(l>>4)+r][s=l&15]; row c=8 is the denom.
// Combine 8 wave-partials in LDS, normalize, fuse Mo clifford transform.
// ---------------------------------------------------------------------------
__global__ __launch_bounds__(512, 8) void ck_attn(const f16* __restrict__ Qp,
                                                  const f16* __restrict__ Kp,
                                                  const unsigned short* __restrict__ Vt,
                                                  const float* __restrict__ wo,
                                                  const float* __restrict__ bo,
                                                  float* __restrict__ out) {
  __shared__ float Lo[TWAVES][SGRP][9];
  __shared__ float MoL[72];  // [0..63] Mo[j][k], [64..71] bo

  const int tid = threadIdx.x;
  const int w = tid >> 6;
  const int lane = tid & 63;
  const int lo = lane & 15, hi = lane >> 4;
  const int rowbase = blockIdx.x * SGRP;
  const int b = rowbase >> 12;

  if (tid < 64) {
    const int blades[8] = {0, 1, 2, 4, 3, 5, 6, 7};
    int j = tid >> 3, k = tid & 7;
    int bj = blades[j];
    float mo = 0.f;
    for (int i = 0; i < 8; ++i) {
      int ai = blades[i];
      if (blades[ai ^ bj] != k) continue;
      mo += cl_sign(ai, bj) * wo[i];
    }
    MoL[tid] = mo;
    if (j == 0) MoL[64 + k] = bo[k];
  }

  // Q fragment for this block's one 16-row subtile (hoisted)
  f16x4 qf = *(const f16x4*)(Qp + (size_t)(rowbase + lo) * 16 + 4 * hi);

  f32x4 acc = {0.f, 0.f, 0.f, 0.f};
  const f32x4 zero = {0.f, 0.f, 0.f, 0.f};

  const f16* kbase = Kp + ((size_t)b * SEQ + w * TCHUNK + lo) * 8 + 4 * (hi & 1);
  const unsigned short* vbase =
      Vt + ((size_t)b * 9 + (lo < 9 ? lo : 8)) * SEQ + w * TCHUNK + 4 * hi;

#pragma unroll 2
  for (int it = 0; it < TCHUNK / TT; ++it) {
    f16x4 kf = *(const f16x4*)(kbase + it * TT * 8);
    s16x4 vf = {0, 0, 0, 0};
    if (lo < 9) vf = *(const s16x4*)(vbase + it * TT);

    f32x4 s4 = __builtin_amdgcn_mfma_f32_16x16x16f16(kf, qf, zero, 0, 0, 0);
    s16x4 pf;
    pf[0] = (short)f2bf(fexp2(s4[0]));
    pf[1] = (short)f2bf(fexp2(s4[1]));
    pf[2] = (short)f2bf(fexp2(s4[2]));
    pf[3] = (short)f2bf(fexp2(s4[3]));
    acc = __builtin_amdgcn_mfma_f32_16x16x16bf16_1k(vf, pf, acc, 0, 0, 0);
  }

  // wave partials: lanes hi<2 carry O blades 0-7, lane hi==2 r=0 the denom
  if (hi < 2) {
    Lo[w][lo][4 * hi + 0] = acc[0];
    Lo[w][lo][4 * hi + 1] = acc[1];
    Lo[w][lo][4 * hi + 2] = acc[2];
    Lo[w][lo][4 * hi + 3] = acc[3];
  } else if (hi == 2) {
    Lo[w][lo][8] = acc[0];
  }
  __syncthreads();

  // stage 1: sum 8 wave-partials per (s, j); each cell has a unique owner
  if (tid < SGRP * 9) {
    int s = tid / 9, j = tid - s * 9;
    float sum = 0.f;
#pragma unroll
    for (int w2 = 0; w2 < TWAVES; ++w2) sum += Lo[w2][s][j];
    Lo[0][s][j] = sum;
  }
  __syncthreads();

  // stage 2: normalize + fused output clifford transform
  if (tid < SGRP * 8) {
    int s = tid >> 3, ko = tid & 7;
    float inv = 1.f / Lo[0][s][8];
    float a = MoL[64 + ko];
#pragma unroll
    for (int j = 0; j < 8; ++j) a = fmaf(Lo[0][s][j] * inv, MoL[j * 8 + ko], a);
    out[(size_t)(rowbase + s) * 8 + ko] = a;
  }
}

// ---------------------------------------------------------------------------
extern "C" void kernel_launch(void* const* d_in, const int* in_sizes, int n_in,
                              void* d_out, int out_size, void* d_ws, size_t ws_size,
                              hipStream_t stream) {
  const float* x  = (const float*)d_in[0];
  const float* wq = (const float*)d_in[1];
  const float* bq = (const float*)d_in[2];
  const float* wk = (const float*)d_in[3];
  const float* bk = (const float*)d_in[4];
  const float* wv = (const float*)d_in[5];
  const float* bv = (const float*)d_in[6];
  const float* wo = (const float*)d_in[7];
  const float* bo = (const float*)d_in[8];

  f16* Qp = (f16*)d_ws;                                 // [B*S][16] f16 = 512 KB
  f16* Kp = Qp + (size_t)NBATCH * SEQ * 16;             // [B*S][8]  f16 = 256 KB
  unsigned short* Vt = (unsigned short*)(Kp + (size_t)NBATCH * SEQ * 8);  // [B][9][S] bf16 = 288 KB
  float* outp = (float*)d_out;

  hipLaunchKernelGGL(ck_qkv, dim3(NBATCH * SEQ / 128), dim3(128), 0, stream,
                     x, wq, bq, wk, bk, wv, bv, Qp, Kp, Vt);
  hipLaunchKernelGGL(ck_attn, dim3(NBATCH * SEQ / SGRP), dim3(512), 0, stream,
                     Qp, Kp, Vt, wo, bo, outp);
}

// Round 8
// 23.272 us; speedup vs baseline: 1.6241x; 1.6241x over previous
//
#include <hip/hip_runtime.h>
#include <math.h>

#define SEQ 4096
#define NBATCH 4
#define SGRP 32      // s-rows per attn block (one 32-col MFMA tile)
#define TWAVES 8     // waves per block (t-split)
#define TCHUNK (SEQ / TWAVES)  // 512 t per wave
#define TT 32        // t per tile (one 32x32x16 QK MFMA)

typedef _Float16 f16;
typedef __attribute__((ext_vector_type(8))) _Float16 f16x8;
typedef __attribute__((ext_vector_type(8))) __bf16 bf16x8;
typedef __attribute__((ext_vector_type(16))) float f32x16;
typedef __attribute__((ext_vector_type(4))) unsigned u32x4;
typedef __attribute__((ext_vector_type(2))) unsigned u32x2;

__device__ __forceinline__ float fexp2(float x) {
#if __has_builtin(__builtin_amdgcn_exp2f)
  return __builtin_amdgcn_exp2f(x);
#else
  return exp2f(x);
#endif
}

// lane l<32 of x keeps x; x.hi-lanes <-> y.lo-lanes exchanged.
// ret[0]=new x, ret[1]=new y.
__device__ __forceinline__ u32x2 pswap(unsigned a, unsigned b) {
#if __has_builtin(__builtin_amdgcn_permlane32_swap)
  return __builtin_amdgcn_permlane32_swap(a, b, false, false);
#else
  asm volatile("v_permlane32_swap_b32 %0, %1" : "+v"(a), "+v"(b));
  u32x2 r; r[0] = a; r[1] = b; return r;
#endif
}

// exp2 pair -> packed bf16x2 dword (round-half-up via +0x8000, then byte-perm
// extracts the two hi16). P>0 always, so half-up == correct direction.
__device__ __forceinline__ unsigned exp2_pk_bf16(float a, float b) {
  unsigned e0 = __builtin_bit_cast(unsigned, fexp2(a)) + 0x8000u;
  unsigned e1 = __builtin_bit_cast(unsigned, fexp2(b)) + 0x8000u;
  return __builtin_amdgcn_perm(e1, e0, 0x07060302u);  // [e1.hi16 : e0.hi16]
}

// float -> bf16 bits, RNE bit-twiddle (packing kernel; not hot).
__device__ __forceinline__ unsigned short f2bf(float f) {
  unsigned u = __builtin_bit_cast(unsigned, f);
  u += 0x7FFF + ((u >> 16) & 1);
  return (unsigned short)(u >> 16);
}

// Clifford Cl(3,0): sign of e_a * e_b (bitmask args).
__device__ __forceinline__ float cl_sign(int amask, int bmask) {
  int cnt = 0, aa = amask >> 1;
  while (aa) { cnt += __popc(aa & bmask); aa >>= 1; }
  return (cnt & 1) ? -1.f : 1.f;
}

// ---------------------------------------------------------------------------
// Kernel 1: fused {param-matrix build} + {Q/K/V projection & packing}.
//  Qp[row][16] f16 = [qhi(8) | qlo(8)]   (B-operand; lane half selects)
//  Kp[row][8]  f16 = khi                  (A-operand; both k-halves load same)
//  Vt[b][c][t] bf16 bits, c=0..8: rows 0-7 = V blades, row 8 = ones (denom)
// ---------------------------------------------------------------------------
__global__ __launch_bounds__(128) void ck_qkv(const float* __restrict__ x,
                                              const float* __restrict__ wq,
                                              const float* __restrict__ bq,
                                              const float* __restrict__ wk,
                                              const float* __restrict__ bk,
                                              const float* __restrict__ wv,
                                              const float* __restrict__ bv,
                                              f16* __restrict__ Qp,
                                              f16* __restrict__ Kp,
                                              unsigned short* __restrict__ Vt) {
  __shared__ float Pl[288];
  const int blades[8] = {0, 1, 2, 4, 3, 5, 6, 7};
  int tid = threadIdx.x;

  if (tid < 64) {
    int j = tid >> 3, k = tid & 7;
    int bj = blades[j];
    float mq = 0.f, mk = 0.f, mv = 0.f;
    for (int i = 0; i < 8; ++i) {
      int ai = blades[i];
      if (blades[ai ^ bj] != k) continue;
      float sgn = cl_sign(ai, bj);
      mq += sgn * wq[i]; mk += sgn * wk[i]; mv += sgn * wv[i];
    }
    float c0 = cl_sign(blades[k], blades[k]);  // diagonal of scalar-part table
    const float F = 0.72134752044448170368f;   // 0.5 * log2(e)
    Pl[tid]       = mq * c0 * F;
    Pl[64 + tid]  = mk;
    Pl[128 + tid] = mv;
    if (j == 0) {
      Pl[256 + k] = bq[k] * c0 * F;
      Pl[264 + k] = bk[k];
      Pl[272 + k] = bv[k];
    }
  }
  __syncthreads();

  int row = blockIdx.x * 128 + tid;  // grid sized exactly to B*S
  int b = row >> 12;
  int s = row & (SEQ - 1);
  const float4* x4 = (const float4*)(x + (size_t)row * 8);
  float4 xa = x4[0], xb = x4[1];
  float xr[8] = {xa.x, xa.y, xa.z, xa.w, xb.x, xb.y, xb.z, xb.w};
  float q[8], k[8], v[8];
#pragma unroll
  for (int c = 0; c < 8; ++c) { q[c] = Pl[256 + c]; k[c] = Pl[264 + c]; v[c] = Pl[272 + c]; }
#pragma unroll
  for (int j = 0; j < 8; ++j) {
    float xj = xr[j];
#pragma unroll
    for (int c = 0; c < 8; ++c) {
      q[c] = fmaf(xj, Pl[j * 8 + c], q[c]);
      k[c] = fmaf(xj, Pl[64 + j * 8 + c], k[c]);
      v[c] = fmaf(xj, Pl[128 + j * 8 + c], v[c]);
    }
  }
  f16x8 qa, qb, ka;
#pragma unroll
  for (int c = 0; c < 8; ++c) {
    f16 h = (f16)q[c];
    qa[c] = h;
    qb[c] = (f16)(q[c] - (float)h);
    ka[c] = (f16)k[c];
  }
  f16x8* qrow = (f16x8*)(Qp + (size_t)row * 16);
  qrow[0] = qa; qrow[1] = qb;
  *(f16x8*)(Kp + (size_t)row * 8) = ka;
  unsigned short* vtb = Vt + (size_t)b * 9 * SEQ;
#pragma unroll
  for (int c = 0; c < 8; ++c) vtb[c * SEQ + s] = f2bf(v[c]);
  vtb[8 * SEQ + s] = 0x3F80;  // 1.0 bf16
}

// ---------------------------------------------------------------------------
// Kernel 2: 32x32x16-MFMA flash attention, no-max softmax (bf16 P: finite for
// any logit). One block = 32 s-rows, 8 waves t-split (512 t each).
// Per wave, per 32-t tile:
//   QK: D = mfma_32x32x16_f16(A=K[32t][khi|khi], B=Q[qhi|qlo][32s], 0)
//     -> lane l holds S[t=(r&3)+8(r>>2)+4(l>>5)][s=l&31], r=0..15
//   P: 16x exp2 -> 8 packed bf16 dwords d0..d7 (t-pairs)
//   B-frags for PV via 2 permlane32_swap each:
//     swap(d0,d2),swap(d1,d3) -> [B0,B1,B2,B3] = P^T[t0..15][s] frag
//     swap(d4,d6),swap(d5,d7) -> P^T[t16..31][s] frag
//   PV: acc = mfma_32x32x16_bf16(A=Vt[c][t-half], Bfrag, acc) x2
//     -> lane holds O^T[c=(r&3)+8(r>>2)+4(l>>5)][s=l&31]; c=8 is the denom.
//   (V rows c>8 clamp to ones-row; junk D rows 9..31 never stored.)
// Combine 8 wave-partials in LDS, normalize, fuse Mo clifford transform.
// ---------------------------------------------------------------------------
__global__ __launch_bounds__(512) void ck_attn(const f16* __restrict__ Qp,
                                               const f16* __restrict__ Kp,
                                               const unsigned short* __restrict__ Vt,
                                               const float* __restrict__ wo,
                                               const float* __restrict__ bo,
                                               float* __restrict__ out) {
  __shared__ float Lo[TWAVES][SGRP][9];
  __shared__ float MoL[72];  // [0..63] Mo[j][k], [64..71] bo

  const int tid = threadIdx.x;
  const int w = tid >> 6;
  const int lane = tid & 63;
  const int ls = lane & 31;   // s-column (QK/PV), t-row (A-frag), c-row (V)
  const int hf = lane >> 5;   // k-half selector
  const int rowbase = blockIdx.x * SGRP;
  const int b = rowbase >> 12;

  if (tid < 64) {
    const int blades[8] = {0, 1, 2, 4, 3, 5, 6, 7};
    int j = tid >> 3, k = tid & 7;
    int bj = blades[j];
    float mo = 0.f;
    for (int i = 0; i < 8; ++i) {
      int ai = blades[i];
      if (blades[ai ^ bj] != k) continue;
      mo += cl_sign(ai, bj) * wo[i];
    }
    MoL[tid] = mo;
    if (j == 0) MoL[64 + k] = bo[k];
  }

  // Q B-frag: qhi (hf=0) or qlo (hf=1) of row rowbase+ls — hoisted
  f16x8 qf = *(const f16x8*)(Qp + (size_t)(rowbase + ls) * 16 + 8 * hf);

  f32x16 acc = {0.f, 0.f, 0.f, 0.f, 0.f, 0.f, 0.f, 0.f,
                0.f, 0.f, 0.f, 0.f, 0.f, 0.f, 0.f, 0.f};
  const f32x16 zero = acc;

  const f16* kbase = Kp + ((size_t)b * SEQ + w * TCHUNK) * 8;
  const unsigned short* vrow =
      Vt + ((size_t)b * 9 + (ls <= 8 ? ls : 8)) * SEQ + w * TCHUNK + 8 * hf;

#pragma unroll 2
  for (int it = 0; it < TCHUNK / TT; ++it) {
    const int t0 = it * TT;
    f16x8 kf = *(const f16x8*)(kbase + (size_t)(t0 + ls) * 8);
    u32x4 v0 = *(const u32x4*)(vrow + t0);
    u32x4 v1 = *(const u32x4*)(vrow + t0 + 16);

    f32x16 s4 = __builtin_amdgcn_mfma_f32_32x32x16_f16(kf, qf, zero, 0, 0, 0);

    unsigned d0 = exp2_pk_bf16(s4[0], s4[1]);    // [t0,t1]+4hf
    unsigned d1 = exp2_pk_bf16(s4[2], s4[3]);    // [t2,t3]+4hf
    unsigned d2 = exp2_pk_bf16(s4[4], s4[5]);    // [t8,t9]+4hf
    unsigned d3 = exp2_pk_bf16(s4[6], s4[7]);    // [t10,t11]+4hf
    u32x2 r02 = pswap(d0, d2);
    u32x2 r13 = pswap(d1, d3);
    u32x4 pb0 = {r02[0], r13[0], r02[1], r13[1]};  // P^T[t0..15][s] frag
    acc = __builtin_amdgcn_mfma_f32_32x32x16_bf16(
        __builtin_bit_cast(bf16x8, v0), __builtin_bit_cast(bf16x8, pb0), acc, 0, 0, 0);

    unsigned d4 = exp2_pk_bf16(s4[8], s4[9]);    // [t16,t17]+4hf
    unsigned d5 = exp2_pk_bf16(s4[10], s4[11]);  // [t18,t19]+4hf
    unsigned d6 = exp2_pk_bf16(s4[12], s4[13]);  // [t24,t25]+4hf
    unsigned d7 = exp2_pk_bf16(s4[14], s4[15]);  // [t26,t27]+4hf
    u32x2 r46 = pswap(d4, d6);
    u32x2 r57 = pswap(d5, d7);
    u32x4 pb1 = {r46[0], r57[0], r46[1], r57[1]};  // P^T[t16..31][s] frag
    acc = __builtin_amdgcn_mfma_f32_32x32x16_bf16(
        __builtin_bit_cast(bf16x8, v1), __builtin_bit_cast(bf16x8, pb1), acc, 0, 0, 0);
  }

  // wave partials: lanes<32 carry blades 0-3 (r0..3) + denom c=8 (r4);
  // lanes>=32 carry blades 4-7 (r0..3).
  if (hf == 0) {
    Lo[w][ls][0] = acc[0]; Lo[w][ls][1] = acc[1];
    Lo[w][ls][2] = acc[2]; Lo[w][ls][3] = acc[3];
    Lo[w][ls][8] = acc[4];
  } else {
    Lo[w][ls][4] = acc[0]; Lo[w][ls][5] = acc[1];
    Lo[w][ls][6] = acc[2]; Lo[w][ls][7] = acc[3];
  }
  __syncthreads();

  // stage 1: sum 8 wave-partials per (s, j); each cell has a unique owner
  if (tid < SGRP * 9) {
    int s = tid / 9, j = tid - s * 9;
    float sum = 0.f;
#pragma unroll
    for (int w2 = 0; w2 < TWAVES; ++w2) sum += Lo[w2][s][j];
    Lo[0][s][j] = sum;
  }
  __syncthreads();

  // stage 2: normalize + fused output clifford transform
  if (tid < SGRP * 8) {
    int s = tid >> 3, ko = tid & 7;
    float inv = 1.f / Lo[0][s][8];
    float a = MoL[64 + ko];
#pragma unroll
    for (int j = 0; j < 8; ++j) a = fmaf(Lo[0][s][j] * inv, MoL[j * 8 + ko], a);
    out[(size_t)(rowbase + s) * 8 + ko] = a;
  }
}

// ---------------------------------------------------------------------------
extern "C" void kernel_launch(void* const* d_in, const int* in_sizes, int n_in,
                              void* d_out, int out_size, void* d_ws, size_t ws_size,
                              hipStream_t stream) {
  const float* x  = (const float*)d_in[0];
  const float* wq = (const float*)d_in[1];
  const float* bq = (const float*)d_in[2];
  const float* wk = (const float*)d_in[3];
  const float* bk = (const float*)d_in[4];
  const float* wv = (const float*)d_in[5];
  const float* bv = (const float*)d_in[6];
  const float* wo = (const float*)d_in[7];
  const float* bo = (const float*)d_in[8];

  f16* Qp = (f16*)d_ws;                                 // [B*S][16] f16 = 512 KB
  f16* Kp = Qp + (size_t)NBATCH * SEQ * 16;             // [B*S][8]  f16 = 256 KB
  unsigned short* Vt = (unsigned short*)(Kp + (size_t)NBATCH * SEQ * 8);  // [B][9][S] bf16 = 288 KB
  float* outp = (float*)d_out;

  hipLaunchKernelGGL(ck_qkv, dim3(NBATCH * SEQ / 128), dim3(128), 0, stream,
                     x, wq, bq, wk, bk, wv, bv, Qp, Kp, Vt);
  hipLaunchKernelGGL(ck_attn, dim3(NBATCH * SEQ / SGRP), dim3(512), 0, stream,
                     Qp, Kp, Vt, wo, bo, outp);
}

// Round 9
// 23.251 us; speedup vs baseline: 1.6255x; 1.0009x over previous
//
#include <hip/hip_runtime.h>
#include <math.h>

#define SEQ 4096
#define NBATCH 4
#define SGRP 32      // s-rows per attn block (one 32-col MFMA tile)
#define TWAVES 8     // waves per block (t-split)
#define TCHUNK (SEQ / TWAVES)  // 512 t per wave
#define TT 32        // t per tile (one 32x32x16 QK MFMA)

typedef _Float16 f16;
typedef __attribute__((ext_vector_type(8))) _Float16 f16x8;
typedef __attribute__((ext_vector_type(8))) __bf16 bf16x8;
typedef __attribute__((ext_vector_type(16))) float f32x16;
typedef __attribute__((ext_vector_type(4))) unsigned u32x4;
typedef __attribute__((ext_vector_type(2))) unsigned u32x2;

__device__ __forceinline__ float fexp2(float x) {
#if __has_builtin(__builtin_amdgcn_exp2f)
  return __builtin_amdgcn_exp2f(x);
#else
  return exp2f(x);
#endif
}

// lane l<32 of x keeps x; x.hi-lanes <-> y.lo-lanes exchanged.
// ret[0]=new x, ret[1]=new y.
__device__ __forceinline__ u32x2 pswap(unsigned a, unsigned b) {
#if __has_builtin(__builtin_amdgcn_permlane32_swap)
  return __builtin_amdgcn_permlane32_swap(a, b, false, false);
#else
  asm volatile("v_permlane32_swap_b32 %0, %1" : "+v"(a), "+v"(b));
  u32x2 r; r[0] = a; r[1] = b; return r;
#endif
}

// exp2 pair -> packed bf16x2 dword (round-half-up via +0x8000, then byte-perm
// extracts the two hi16). P>0 always, so half-up == correct direction.
__device__ __forceinline__ unsigned exp2_pk_bf16(float a, float b) {
  unsigned e0 = __builtin_bit_cast(unsigned, fexp2(a)) + 0x8000u;
  unsigned e1 = __builtin_bit_cast(unsigned, fexp2(b)) + 0x8000u;
  return __builtin_amdgcn_perm(e1, e0, 0x07060302u);  // [e1.hi16 : e0.hi16]
}

// float -> bf16 bits, RNE bit-twiddle (packing kernel; not hot).
__device__ __forceinline__ unsigned short f2bf(float f) {
  unsigned u = __builtin_bit_cast(unsigned, f);
  u += 0x7FFF + ((u >> 16) & 1);
  return (unsigned short)(u >> 16);
}

// Clifford Cl(3,0): sign of e_a * e_b (bitmask args).
__device__ __forceinline__ float cl_sign(int amask, int bmask) {
  int cnt = 0, aa = amask >> 1;
  while (aa) { cnt += __popc(aa & bmask); aa >>= 1; }
  return (cnt & 1) ? -1.f : 1.f;
}

// ---------------------------------------------------------------------------
// Kernel 1: fused {param-matrix build} + {Q/K/V projection & packing}.
//  Qp[row][16] f16 = [qhi(8) | qlo(8)]   (B-operand; lane half selects)
//  Kp[row][8]  f16 = khi                  (A-operand; both k-halves load same)
//  Vt[b][c][t] bf16 bits, c=0..8: rows 0-7 = V blades, row 8 = ones (denom)
// ---------------------------------------------------------------------------
__global__ __launch_bounds__(128) void ck_qkv(const float* __restrict__ x,
                                              const float* __restrict__ wq,
                                              const float* __restrict__ bq,
                                              const float* __restrict__ wk,
                                              const float* __restrict__ bk,
                                              const float* __restrict__ wv,
                                              const float* __restrict__ bv,
                                              f16* __restrict__ Qp,
                                              f16* __restrict__ Kp,
                                              unsigned short* __restrict__ Vt) {
  __shared__ float Pl[288];
  const int blades[8] = {0, 1, 2, 4, 3, 5, 6, 7};
  int tid = threadIdx.x;

  if (tid < 64) {
    int j = tid >> 3, k = tid & 7;
    int bj = blades[j];
    float mq = 0.f, mk = 0.f, mv = 0.f;
    for (int i = 0; i < 8; ++i) {
      int ai = blades[i];
      if (blades[ai ^ bj] != k) continue;
      float sgn = cl_sign(ai, bj);
      mq += sgn * wq[i]; mk += sgn * wk[i]; mv += sgn * wv[i];
    }
    float c0 = cl_sign(blades[k], blades[k]);  // diagonal of scalar-part table
    const float F = 0.72134752044448170368f;   // 0.5 * log2(e)
    Pl[tid]       = mq * c0 * F;
    Pl[64 + tid]  = mk;
    Pl[128 + tid] = mv;
    if (j == 0) {
      Pl[256 + k] = bq[k] * c0 * F;
      Pl[264 + k] = bk[k];
      Pl[272 + k] = bv[k];
    }
  }
  __syncthreads();

  int row = blockIdx.x * 128 + tid;  // grid sized exactly to B*S
  int b = row >> 12;
  int s = row & (SEQ - 1);
  const float4* x4 = (const float4*)(x + (size_t)row * 8);
  float4 xa = x4[0], xb = x4[1];
  float xr[8] = {xa.x, xa.y, xa.z, xa.w, xb.x, xb.y, xb.z, xb.w};
  float q[8], k[8], v[8];
#pragma unroll
  for (int c = 0; c < 8; ++c) { q[c] = Pl[256 + c]; k[c] = Pl[264 + c]; v[c] = Pl[272 + c]; }
#pragma unroll
  for (int j = 0; j < 8; ++j) {
    float xj = xr[j];
#pragma unroll
    for (int c = 0; c < 8; ++c) {
      q[c] = fmaf(xj, Pl[j * 8 + c], q[c]);
      k[c] = fmaf(xj, Pl[64 + j * 8 + c], k[c]);
      v[c] = fmaf(xj, Pl[128 + j * 8 + c], v[c]);
    }
  }
  f16x8 qa, qb, ka;
#pragma unroll
  for (int c = 0; c < 8; ++c) {
    f16 h = (f16)q[c];
    qa[c] = h;
    qb[c] = (f16)(q[c] - (float)h);
    ka[c] = (f16)k[c];
  }
  f16x8* qrow = (f16x8*)(Qp + (size_t)row * 16);
  qrow[0] = qa; qrow[1] = qb;
  *(f16x8*)(Kp + (size_t)row * 8) = ka;
  unsigned short* vtb = Vt + (size_t)b * 9 * SEQ;
#pragma unroll
  for (int c = 0; c < 8; ++c) vtb[c * SEQ + s] = f2bf(v[c]);
  vtb[8 * SEQ + s] = 0x3F80;  // 1.0 bf16
}

// ---------------------------------------------------------------------------
// Kernel 2: 32x32x16-MFMA flash attention, no-max softmax (bf16 P: finite for
// any logit). One block = 32 s-rows, 8 waves t-split (512 t each).
// __launch_bounds__(512, 4): cap VGPR at 128 so 2 blocks/CU = 4 waves/SIMD
// are guaranteed resident (R8 A/B experiment: occupancy vs latency-chain).
// Per wave, per 32-t tile:
//   QK: D = mfma_32x32x16_f16(A=K[32t][khi|khi], B=Q[qhi|qlo][32s], 0)
//     -> lane l holds S[t=(r&3)+8(r>>2)+4(l>>5)][s=l&31], r=0..15
//   P: 16x exp2 -> 8 packed bf16 dwords d0..d7 (t-pairs)
//   B-frags for PV via 2 permlane32_swap each:
//     swap(d0,d2),swap(d1,d3) -> [B0,B1,B2,B3] = P^T[t0..15][s] frag
//     swap(d4,d6),swap(d5,d7) -> P^T[t16..31][s] frag
//   PV: acc = mfma_32x32x16_bf16(A=Vt[c][t-half], Bfrag, acc) x2
//     -> lane holds O^T[c=(r&3)+8(r>>2)+4(l>>5)][s=l&31]; c=8 is the denom.
//   (V rows c>8 clamp to ones-row; junk D rows 9..31 never stored.)
// Combine 8 wave-partials in LDS, normalize, fuse Mo clifford transform.
// ---------------------------------------------------------------------------
__global__ __launch_bounds__(512, 4) void ck_attn(const f16* __restrict__ Qp,
                                                  const f16* __restrict__ Kp,
                                                  const unsigned short* __restrict__ Vt,
                                                  const float* __restrict__ wo,
                                                  const float* __restrict__ bo,
                                                  float* __restrict__ out) {
  __shared__ float Lo[TWAVES][SGRP][9];
  __shared__ float MoL[72];  // [0..63] Mo[j][k], [64..71] bo

  const int tid = threadIdx.x;
  const int w = tid >> 6;
  const int lane = tid & 63;
  const int ls = lane & 31;   // s-column (QK/PV), t-row (A-frag), c-row (V)
  const int hf = lane >> 5;   // k-half selector
  const int rowbase = blockIdx.x * SGRP;
  const int b = rowbase >> 12;

  if (tid < 64) {
    const int blades[8] = {0, 1, 2, 4, 3, 5, 6, 7};
    int j = tid >> 3, k = tid & 7;
    int bj = blades[j];
    float mo = 0.f;
    for (int i = 0; i < 8; ++i) {
      int ai = blades[i];
      if (blades[ai ^ bj] != k) continue;
      mo += cl_sign(ai, bj) * wo[i];
    }
    MoL[tid] = mo;
    if (j == 0) MoL[64 + k] = bo[k];
  }

  // Q B-frag: qhi (hf=0) or qlo (hf=1) of row rowbase+ls — hoisted
  f16x8 qf = *(const f16x8*)(Qp + (size_t)(rowbase + ls) * 16 + 8 * hf);

  f32x16 acc = {0.f, 0.f, 0.f, 0.f, 0.f, 0.f, 0.f, 0.f,
                0.f, 0.f, 0.f, 0.f, 0.f, 0.f, 0.f, 0.f};
  const f32x16 zero = acc;

  const f16* kbase = Kp + ((size_t)b * SEQ + w * TCHUNK) * 8;
  const unsigned short* vrow =
      Vt + ((size_t)b * 9 + (ls <= 8 ? ls : 8)) * SEQ + w * TCHUNK + 8 * hf;

#pragma unroll 2
  for (int it = 0; it < TCHUNK / TT; ++it) {
    const int t0 = it * TT;
    f16x8 kf = *(const f16x8*)(kbase + (size_t)(t0 + ls) * 8);
    u32x4 v0 = *(const u32x4*)(vrow + t0);
    u32x4 v1 = *(const u32x4*)(vrow + t0 + 16);

    f32x16 s4 = __builtin_amdgcn_mfma_f32_32x32x16_f16(kf, qf, zero, 0, 0, 0);

    unsigned d0 = exp2_pk_bf16(s4[0], s4[1]);    // [t0,t1]+4hf
    unsigned d1 = exp2_pk_bf16(s4[2], s4[3]);    // [t2,t3]+4hf
    unsigned d2 = exp2_pk_bf16(s4[4], s4[5]);    // [t8,t9]+4hf
    unsigned d3 = exp2_pk_bf16(s4[6], s4[7]);    // [t10,t11]+4hf
    u32x2 r02 = pswap(d0, d2);
    u32x2 r13 = pswap(d1, d3);
    u32x4 pb0 = {r02[0], r13[0], r02[1], r13[1]};  // P^T[t0..15][s] frag
    acc = __builtin_amdgcn_mfma_f32_32x32x16_bf16(
        __builtin_bit_cast(bf16x8, v0), __builtin_bit_cast(bf16x8, pb0), acc, 0, 0, 0);

    unsigned d4 = exp2_pk_bf16(s4[8], s4[9]);    // [t16,t17]+4hf
    unsigned d5 = exp2_pk_bf16(s4[10], s4[11]);  // [t18,t19]+4hf
    unsigned d6 = exp2_pk_bf16(s4[12], s4[13]);  // [t24,t25]+4hf
    unsigned d7 = exp2_pk_bf16(s4[14], s4[15]);  // [t26,t27]+4hf
    u32x2 r46 = pswap(d4, d6);
    u32x2 r57 = pswap(d5, d7);
    u32x4 pb1 = {r46[0], r57[0], r46[1], r57[1]};  // P^T[t16..31][s] frag
    acc = __builtin_amdgcn_mfma_f32_32x32x16_bf16(
        __builtin_bit_cast(bf16x8, v1), __builtin_bit_cast(bf16x8, pb1), acc, 0, 0, 0);
  }

  // wave partials: lanes<32 carry blades 0-3 (r0..3) + denom c=8 (r4);
  // lanes>=32 carry blades 4-7 (r0..3).
  if (hf == 0) {
    Lo[w][ls][0] = acc[0]; Lo[w][ls][1] = acc[1];
    Lo[w][ls][2] = acc[2]; Lo[w][ls][3] = acc[3];
    Lo[w][ls][8] = acc[4];
  } else {
    Lo[w][ls][4] = acc[0]; Lo[w][ls][5] = acc[1];
    Lo[w][ls][6] = acc[2]; Lo[w][ls][7] = acc[3];
  }
  __syncthreads();

  // stage 1: sum 8 wave-partials per (s, j); each cell has a unique owner
  if (tid < SGRP * 9) {
    int s = tid / 9, j = tid - s * 9;
    float sum = 0.f;
#pragma unroll
    for (int w2 = 0; w2 < TWAVES; ++w2) sum += Lo[w2][s][j];
    Lo[0][s][j] = sum;
  }
  __syncthreads();

  // stage 2: normalize + fused output clifford transform
  if (tid < SGRP * 8) {
    int s = tid >> 3, ko = tid & 7;
    float inv = 1.f / Lo[0][s][8];
    float a = MoL[64 + ko];
#pragma unroll
    for (int j = 0; j < 8; ++j) a = fmaf(Lo[0][s][j] * inv, MoL[j * 8 + ko], a);
    out[(size_t)(rowbase + s) * 8 + ko] = a;
  }
}

// ---------------------------------------------------------------------------
extern "C" void kernel_launch(void* const* d_in, const int* in_sizes, int n_in,
                              void* d_out, int out_size, void* d_ws, size_t ws_size,
                              hipStream_t stream) {
  const float* x  = (const float*)d_in[0];
  const float* wq = (const float*)d_in[1];
  const float* bq = (const float*)d_in[2];
  const float* wk = (const float*)d_in[3];
  const float* bk = (const float*)d_in[4];
  const float* wv = (const float*)d_in[5];
  const float* bv = (const float*)d_in[6];
  const float* wo = (const float*)d_in[7];
  const float* bo = (const float*)d_in[8];

  f16* Qp = (f16*)d_ws;                                 // [B*S][16] f16 = 512 KB
  f16* Kp = Qp + (size_t)NBATCH * SEQ * 16;             // [B*S][8]  f16 = 256 KB
  unsigned short* Vt = (unsigned short*)(Kp + (size_t)NBATCH * SEQ * 8);  // [B][9][S] bf16 = 288 KB
  float* outp = (float*)d_out;

  hipLaunchKernelGGL(ck_qkv, dim3(NBATCH * SEQ / 128), dim3(128), 0, stream,
                     x, wq, bq, wk, bk, wv, bv, Qp, Kp, Vt);
  hipLaunchKernelGGL(ck_attn, dim3(NBATCH * SEQ / SGRP), dim3(512), 0, stream,
                     Qp, Kp, Vt, wo, bo, outp);
}